// Round 15
// baseline (489.104 us; speedup 1.0000x reference)
//
#include <hip/hip_runtime.h>
#include <math.h>

#define N_NODES 50000
#define N_EDGES 800000
#define N_GRAPHS 50
#define HD 128
#define TM 64
#define POOL_CHUNK 125
#define SCAN_B 256
#define SCAN_NB ((N_NODES + SCAN_B - 1) / SCAN_B)   // 196
#define NB_H 64
#define CH_H (N_EDGES / NB_H)                        // 12500
#define NBIN2 (N_NODES / 2)                          // 25000 packed dwords

// ---------------- degree histograms: LDS uint16-packed partials, 2D grid ------------
// blockIdx.y = 0: dst -> part_in ; 1: src -> part_out (independent, parallel)
__global__ __launch_bounds__(256) void k_hist(const int* __restrict__ src,
                                              const int* __restrict__ dst,
                                              unsigned* __restrict__ part_in,
                                              unsigned* __restrict__ part_out) {
    __shared__ unsigned cnt[NBIN2];      // 100 KB
    int t = threadIdx.x, b = blockIdx.x;
    const int* idx = blockIdx.y ? src : dst;
    unsigned* outp = blockIdx.y ? part_out : part_in;
    int e0 = b * CH_H;
    for (int j = t; j < NBIN2; j += 256) cnt[j] = 0;
    __syncthreads();
    for (int e = e0 + t; e < e0 + CH_H; e += 256) {
        int i = idx[e];
        atomicAdd(&cnt[i >> 1], 1u << ((i & 1) * 16));
    }
    __syncthreads();
    for (int j = t; j < NBIN2; j += 256) outp[b * NBIN2 + j] = cnt[j];
}

// reduce partials to degrees; convert part_in to per-block exclusive prefixes
__global__ void k_dreduce(unsigned* __restrict__ part_in,
                          const unsigned* __restrict__ part_out,
                          int* __restrict__ deg_in, int* __restrict__ deg_out) {
    int j = blockIdx.x * blockDim.x + threadIdx.x;
    if (j >= NBIN2) return;
    unsigned run_i = 0, run_o = 0;
    for (int b = 0; b < NB_H; ++b) {
        unsigned pi = part_in[b * NBIN2 + j];
        unsigned po = part_out[b * NBIN2 + j];
        part_in[b * NBIN2 + j] = run_i;
        run_i += pi;
        run_o += po;
    }
    ((int2*)deg_in)[j] = make_int2((int)(run_i & 0xFFFFu), (int)(run_i >> 16));
    ((int2*)deg_out)[j] = make_int2((int)(run_o & 0xFFFFu), (int)(run_o >> 16));
}

// ---------------- norms + graph counts + layer-1 edge payload ----------------
__global__ void k_norms(const int* __restrict__ deg_in, const int* __restrict__ deg_out,
                        const int* __restrict__ gids,
                        float* norm_src, float* norm_dst, int* gcount,
                        float4* __restrict__ feat4) {
    __shared__ int hist[N_GRAPHS];
    int t = threadIdx.x;
    if (t < N_GRAPHS) hist[t] = 0;
    __syncthreads();
    int i = blockIdx.x * blockDim.x + t;
    if (i < N_NODES) {
        float di = (float)deg_in[i];
        float dq = (float)deg_out[i];
        float nd = 1.0f / sqrtf(fmaxf(di, 1.0f));
        float ns = 1.0f / sqrtf(fmaxf(dq, 1.0f));
        norm_dst[i] = nd;
        norm_src[i] = ns;
        float4 f;
        f.x = di * ns;
        f.y = (di > 3.0f) ? ns : 0.0f;
        f.z = (3.0f / di) * ns;
        f.w = (di > 4.0f) ? ns : 0.0f;
        feat4[i] = f;
        atomicAdd(&hist[gids[i]], 1);
    }
    __syncthreads();
    if (t < N_GRAPHS && hist[t] != 0) atomicAdd(&gcount[t], hist[t]);
}

// ---------------- device-wide exclusive scan, 3 phases ----------------
__global__ void k_scan1(const int* __restrict__ deg_in, int* off, int* bsum) {
    __shared__ int sh[SCAN_B];
    int t = threadIdx.x;
    int i = blockIdx.x * SCAN_B + t;
    int v = (i < N_NODES) ? deg_in[i] : 0;
    sh[t] = v;
    __syncthreads();
    for (int o = 1; o < SCAN_B; o <<= 1) {
        int u = (t >= o) ? sh[t - o] : 0;
        __syncthreads();
        sh[t] += u;
        __syncthreads();
    }
    if (i < N_NODES) off[i] = sh[t] - v;
    if (t == SCAN_B - 1) bsum[blockIdx.x] = sh[t];
}

__global__ void k_scan2(int* bsum, int* off) {
    __shared__ int sh[SCAN_B];
    int t = threadIdx.x;
    int v = (t < SCAN_NB) ? bsum[t] : 0;
    sh[t] = v;
    __syncthreads();
    for (int o = 1; o < SCAN_B; o <<= 1) {
        int u = (t >= o) ? sh[t - o] : 0;
        __syncthreads();
        sh[t] += u;
        __syncthreads();
    }
    if (t < SCAN_NB) bsum[t] = sh[t] - v;
    if (t == SCAN_B - 1) off[N_NODES] = sh[t];
}

__global__ void k_scan3(int* off, const int* __restrict__ bsum) {
    int b = blockIdx.x, t = threadIdx.x;
    int i = b * SCAN_B + t;
    if (i < N_NODES) off[i] += bsum[b];
}

// ---------------- CSR scatter, atomic-free (LDS packed rank cursors) ----------------
__global__ __launch_bounds__(256) void k_scatter2(const int* __restrict__ src,
                                                  const int* __restrict__ dst,
                                                  const int* __restrict__ off,
                                                  const unsigned* __restrict__ part_in,
                                                  int* __restrict__ csr) {
    __shared__ unsigned cur[NBIN2];
    int t = threadIdx.x, b = blockIdx.x;
    const unsigned* base = part_in + (size_t)b * NBIN2;
    for (int j = t; j < NBIN2; j += 256) cur[j] = base[j];
    __syncthreads();
    int e0 = b * CH_H;
    for (int e = e0 + t; e < e0 + CH_H; e += 256) {
        int d = dst[e];
        int sh = (d & 1) * 16;
        unsigned old = atomicAdd(&cur[d >> 1], 1u << sh);
        int rank = (int)((old >> sh) & 0xFFFFu);
        csr[off[d] + rank] = src[e];
    }
}

// ---------------- layer-1 aggregation: one float4 gather per edge ----------------
__global__ void k_agg1(const int* __restrict__ off, const int* __restrict__ csr,
                       const float4* __restrict__ feat4,
                       const float* __restrict__ ndst, float* __restrict__ agg8) {
    int i = blockIdx.x * blockDim.x + threadIdx.x;
    if (i >= N_NODES) return;
    int e0 = off[i], e1 = off[i + 1];
    float a0 = 0.f, a1 = 0.f, a2 = 0.f, a3 = 0.f;
    int e = e0;
    for (; e + 1 < e1; e += 2) {
        float4 f0 = feat4[csr[e]];
        float4 f1 = feat4[csr[e + 1]];
        a0 += f0.x + f1.x; a1 += f0.y + f1.y;
        a2 += f0.z + f1.z; a3 += f0.w + f1.w;
    }
    if (e < e1) {
        float4 f0 = feat4[csr[e]];
        a0 += f0.x; a1 += f0.y; a2 += f0.z; a3 += f0.w;
    }
    float nd = ndst[i];
    a0 *= nd; a1 *= nd; a2 *= nd; a3 *= nd;
    float4* p = (float4*)(agg8 + (size_t)i * 8);
    float4 hi = { a0, a1, a2, a3 };
    float4 lo = { -a0, -a1, -a2, -a3 };
    p[0] = hi;
    p[1] = lo;
}

// ---------------- layer-1 GEMM 8 -> 128, fused bias+relu+nsrc premult ---------------
__global__ void k_gemm1(const float* __restrict__ agg8, const float* __restrict__ W,
                        const float* __restrict__ b, const float* __restrict__ nsrc,
                        float* __restrict__ out) {
    __shared__ float Wsh[8 * 128];
    int t = threadIdx.x;
    for (int i = t; i < 1024; i += 256) Wsh[i] = W[i];
    __syncthreads();
    int row = blockIdx.x * 2 + (t >> 7);
    int j = t & 127;
    if (row >= N_NODES) return;
    const float* a = agg8 + (size_t)row * 8;
    float acc = b[j];
#pragma unroll
    for (int k = 0; k < 8; ++k) acc += a[k] * Wsh[k * 128 + j];
    out[(size_t)row * HD + j] = fmaxf(acc, 0.0f) * nsrc[row];
}

// ---------------- 128-dim aggregation, float4 half-wave-per-edge, 4-deep MLP --------
__global__ __launch_bounds__(256) void k_agg4(const int* __restrict__ off,
                                              const int* __restrict__ csr,
                                              const float* __restrict__ ndst,
                                              const float* __restrict__ h,
                                              float* __restrict__ out) {
    int wid = (blockIdx.x * blockDim.x + threadIdx.x) >> 6;
    int lane = threadIdx.x & 63;
    if (wid >= N_NODES) return;
    int half = lane >> 5;
    int q = lane & 31;
    int e0 = off[wid], e1 = off[wid + 1];
    float4 a = { 0.f, 0.f, 0.f, 0.f };
    int e = e0 + half;
    for (; e + 6 < e1; e += 8) {       // 4 edges per half, 8 per wave-iter
        int s0 = csr[e], s1 = csr[e + 2], s2 = csr[e + 4], s3 = csr[e + 6];
        float4 v0 = *(const float4*)(h + (size_t)s0 * HD + q * 4);
        float4 v1 = *(const float4*)(h + (size_t)s1 * HD + q * 4);
        float4 v2 = *(const float4*)(h + (size_t)s2 * HD + q * 4);
        float4 v3 = *(const float4*)(h + (size_t)s3 * HD + q * 4);
        a.x += v0.x + v1.x + v2.x + v3.x;
        a.y += v0.y + v1.y + v2.y + v3.y;
        a.z += v0.z + v1.z + v2.z + v3.z;
        a.w += v0.w + v1.w + v2.w + v3.w;
    }
    for (; e < e1; e += 2) {
        int s0 = csr[e];
        float4 v0 = *(const float4*)(h + (size_t)s0 * HD + q * 4);
        a.x += v0.x; a.y += v0.y; a.z += v0.z; a.w += v0.w;
    }
    a.x += __shfl_xor(a.x, 32);
    a.y += __shfl_xor(a.y, 32);
    a.z += __shfl_xor(a.z, 32);
    a.w += __shfl_xor(a.w, 32);
    if (half == 0) {
        float nd = ndst[wid];
        a.x *= nd; a.y *= nd; a.z *= nd; a.w *= nd;
        *(float4*)(out + (size_t)wid * HD + q * 4) = a;
    }
}

// ---------------- fallback float2 aggregation (h only 8B-aligned) ----------------
__global__ void k_agg2(const int* __restrict__ off, const int* __restrict__ csr,
                       const float* __restrict__ ndst,
                       const float* __restrict__ h, float* __restrict__ out) {
    int wid = (blockIdx.x * blockDim.x + threadIdx.x) >> 6;
    int lane = threadIdx.x & 63;
    if (wid >= N_NODES) return;
    int e0 = off[wid], e1 = off[wid + 1];
    float a0 = 0.f, a1 = 0.f;
    int e = e0;
    for (; e + 3 < e1; e += 4) {
        int s0 = csr[e], s1 = csr[e + 1], s2 = csr[e + 2], s3 = csr[e + 3];
        float2 v0 = *(const float2*)(h + (size_t)s0 * HD + lane * 2);
        float2 v1 = *(const float2*)(h + (size_t)s1 * HD + lane * 2);
        float2 v2 = *(const float2*)(h + (size_t)s2 * HD + lane * 2);
        float2 v3 = *(const float2*)(h + (size_t)s3 * HD + lane * 2);
        a0 += v0.x + v1.x + v2.x + v3.x;
        a1 += v0.y + v1.y + v2.y + v3.y;
    }
    for (; e < e1; ++e) {
        int s0 = csr[e];
        float2 v0 = *(const float2*)(h + (size_t)s0 * HD + lane * 2);
        a0 += v0.x; a1 += v0.y;
    }
    float nd = ndst[wid];
    float2 o; o.x = a0 * nd; o.y = a1 * nd;
    *(float2*)(out + (size_t)wid * HD + lane * 2) = o;
}

// ---------------- 64x64-tile GEMM: W in LDS (32 KB), A from global/L1 ----------------
// Software-pipelined: next k-tile's A rows prefetched into registers before the
// current tile's FMA block (unroll 1 keeps VGPR ~120 -> 4+ blocks/CU).
__global__ __launch_bounds__(256) void k_gemm3(const float* __restrict__ A,
                                               const float* __restrict__ W,
                                               const float* __restrict__ b,
                                               const float* __restrict__ nsrc,
                                               int premult,
                                               float* __restrict__ out) {
    __shared__ float Wsh[128 * 64];      // [k][j] half of W, 32 KB
    int t = threadIdx.x;
    int row0 = blockIdx.x * TM;
    int jh = blockIdx.y * 64;
    const float4* W4 = (const float4*)W;
#pragma unroll
    for (int i = 0; i < 8; ++i) {
        int idx = t + i * 256;           // 0..2047 over 128k x 16q
        int k = idx >> 4;
        int q = idx & 15;
        ((float4*)Wsh)[k * 16 + q] = W4[k * 32 + (jh >> 2) + q];
    }
    __syncthreads();
    int jq = (t & 15) * 4;               // col group within half
    int r0 = (t >> 4) * 4;               // row group
    const float* A0 = A + (size_t)min(row0 + r0 + 0, N_NODES - 1) * HD;
    const float* A1 = A + (size_t)min(row0 + r0 + 1, N_NODES - 1) * HD;
    const float* A2 = A + (size_t)min(row0 + r0 + 2, N_NODES - 1) * HD;
    const float* A3 = A + (size_t)min(row0 + r0 + 3, N_NODES - 1) * HD;
    float4 bv = *(const float4*)(b + jh + jq);
    float acc[4][4];
#pragma unroll
    for (int r = 0; r < 4; ++r) {
        acc[r][0] = bv.x; acc[r][1] = bv.y; acc[r][2] = bv.z; acc[r][3] = bv.w;
    }
#define KSTEP(wv, e0_, e1_, e2_, e3_)                                                   \
    acc[0][0] += e0_ * wv.x; acc[0][1] += e0_ * wv.y; acc[0][2] += e0_ * wv.z; acc[0][3] += e0_ * wv.w; \
    acc[1][0] += e1_ * wv.x; acc[1][1] += e1_ * wv.y; acc[1][2] += e1_ * wv.z; acc[1][3] += e1_ * wv.w; \
    acc[2][0] += e2_ * wv.x; acc[2][1] += e2_ * wv.y; acc[2][2] += e2_ * wv.z; acc[2][3] += e2_ * wv.w; \
    acc[3][0] += e3_ * wv.x; acc[3][1] += e3_ * wv.y; acc[3][2] += e3_ * wv.z; acc[3][3] += e3_ * wv.w;
    float4 a0 = *(const float4*)(A0);
    float4 a1 = *(const float4*)(A1);
    float4 a2 = *(const float4*)(A2);
    float4 a3 = *(const float4*)(A3);
#pragma unroll 1
    for (int k = 0; k < 124; k += 4) {
        float4 n0 = *(const float4*)(A0 + k + 4);   // prefetch next tile
        float4 n1 = *(const float4*)(A1 + k + 4);
        float4 n2 = *(const float4*)(A2 + k + 4);
        float4 n3 = *(const float4*)(A3 + k + 4);
        float4 w0 = *(const float4*)&Wsh[(k + 0) * 64 + jq];
        float4 w1 = *(const float4*)&Wsh[(k + 1) * 64 + jq];
        float4 w2 = *(const float4*)&Wsh[(k + 2) * 64 + jq];
        float4 w3 = *(const float4*)&Wsh[(k + 3) * 64 + jq];
        KSTEP(w0, a0.x, a1.x, a2.x, a3.x)
        KSTEP(w1, a0.y, a1.y, a2.y, a3.y)
        KSTEP(w2, a0.z, a1.z, a2.z, a3.z)
        KSTEP(w3, a0.w, a1.w, a2.w, a3.w)
        a0 = n0; a1 = n1; a2 = n2; a3 = n3;
    }
    {   // tail k = 124
        float4 w0 = *(const float4*)&Wsh[124 * 64 + jq];
        float4 w1 = *(const float4*)&Wsh[125 * 64 + jq];
        float4 w2 = *(const float4*)&Wsh[126 * 64 + jq];
        float4 w3 = *(const float4*)&Wsh[127 * 64 + jq];
        KSTEP(w0, a0.x, a1.x, a2.x, a3.x)
        KSTEP(w1, a0.y, a1.y, a2.y, a3.y)
        KSTEP(w2, a0.z, a1.z, a2.z, a3.z)
        KSTEP(w3, a0.w, a1.w, a2.w, a3.w)
    }
#undef KSTEP
#pragma unroll
    for (int r = 0; r < 4; ++r) {
        int row = row0 + r0 + r;
        if (row < N_NODES) {
            float sc = premult ? nsrc[row] : 1.0f;
            float* op = out + (size_t)row * HD + jh + jq;
            float2 o01 = { fmaxf(acc[r][0], 0.f) * sc, fmaxf(acc[r][1], 0.f) * sc };
            float2 o23 = { fmaxf(acc[r][2], 0.f) * sc, fmaxf(acc[r][3], 0.f) * sc };
            *(float2*)op = o01;          // dest may be only 8B-aligned (d_out region)
            *(float2*)(op + 2) = o23;
        }
    }
}

// ---------------- mean-pool partials (125-node chunks, uniform graph id) ------------
__global__ void k_pool(const float* __restrict__ hco, const int* __restrict__ gids,
                       float* gsum) {
    int f = threadIdx.x;                 // 128
    int n0 = blockIdx.x * POOL_CHUNK;
    int g = gids[n0];
    float s = 0.f;
    for (int i = 0; i < POOL_CHUNK; ++i)
        s += hco[(size_t)(n0 + i) * HD + f];
    atomicAdd(&gsum[g * HD + f], s);
}

// ---------------- head: graph_emb, MLP, sigmoid ----------------
__global__ void k_head(const float* __restrict__ gsum, const int* __restrict__ gcount,
                       const float* __restrict__ lw1, const float* __restrict__ lb1,
                       const float* __restrict__ lw2, const float* __restrict__ lb2,
                       float* __restrict__ dout) {
    __shared__ float ge[128];
    int g = blockIdx.x, j = threadIdx.x;  // 64 threads
    float cnt = (float)gcount[g];
    float g0 = gsum[g * HD + j] / cnt;
    float g1 = gsum[g * HD + 64 + j] / cnt;
    ge[j] = g0; ge[64 + j] = g1;
    dout[N_GRAPHS + g * HD + j] = g0;
    dout[N_GRAPHS + g * HD + 64 + j] = g1;
    __syncthreads();
    float acc = lb1[j];
#pragma unroll 4
    for (int k = 0; k < 128; ++k) acc += ge[k] * lw1[k * 64 + j];
    float he = fmaxf(acc, 0.f);
    float p = he * lw2[j];
#pragma unroll
    for (int o = 32; o > 0; o >>= 1) p += __shfl_down(p, o);
    if (j == 0) dout[g] = 1.0f / (1.0f + expf(-(p + lb2[0])));
}

extern "C" void kernel_launch(void* const* d_in, const int* in_sizes, int n_in,
                              void* d_out, int out_size, void* d_ws, size_t ws_size,
                              hipStream_t stream) {
    const int* src  = (const int*)d_in[0];
    const int* dst  = (const int*)d_in[1];
    const int* gids = (const int*)d_in[2];
    const float* W1 = (const float*)d_in[3];  const float* b1 = (const float*)d_in[4];
    const float* W2 = (const float*)d_in[5];  const float* b2 = (const float*)d_in[6];
    const float* W3 = (const float*)d_in[7];  const float* b3 = (const float*)d_in[8];
    const float* W4 = (const float*)d_in[9];  const float* b4 = (const float*)d_in[10];
    const float* W5 = (const float*)d_in[11]; const float* b5 = (const float*)d_in[12];
    const float* lw1 = (const float*)d_in[13]; const float* lb1 = (const float*)d_in[14];
    const float* lw2 = (const float*)d_in[15]; const float* lb2 = (const float*)d_in[16];
    float* out = (float*)d_out;

    char* ws = (char*)d_ws;
    int*    gcount   = (int*)(ws + 0);              // 256 B
    float*  gsum     = (float*)(ws + 256);          // 25600 B
    const size_t ZERO_BYTES = 25856;
    int*    deg_in   = (int*)(ws + 26112);          // 200192 B
    int*    deg_out  = (int*)(ws + 226304);         // 200192 B
    int*    off      = (int*)(ws + 426496);         // 200192 B
    int*    csr      = (int*)(ws + 826880);         // 3200000 B
    float*  norm_src = (float*)(ws + 4026880);      // 200192 B
    float*  norm_dst = (float*)(ws + 4227072);      // 200192 B
    int*    bsum     = (int*)(ws + 4427264);        // 1024 B
    float4* feat4    = (float4*)(ws + 4428288);     // 800256 B
    float*  aggbuf   = (float*)(ws + 5228544);      // 25.6 MB (hist partials + agg)
    float*  hws      = (float*)(ws + 30828544);     // 25.6 MB (16B-aligned h rows)
    const size_t WS_NEEDED = 30828544 + 25600000;

    unsigned* part_in  = (unsigned*)aggbuf;
    unsigned* part_out = (unsigned*)aggbuf + NB_H * NBIN2;

    float* hco = out + (N_GRAPHS + N_GRAPHS * HD);  // layer-5 output = h_co region
    bool aligned = (ws_size >= WS_NEEDED);
    float* hbuf = aligned ? hws : hco;

    hipMemsetAsync(ws, 0, ZERO_BYTES, stream);

    k_hist<<<dim3(NB_H, 2), 256, 0, stream>>>(src, dst, part_in, part_out);
    k_dreduce<<<(NBIN2 + 255) / 256, 256, 0, stream>>>(part_in, part_out,
                                                       deg_in, deg_out);
    k_norms<<<(N_NODES + 255) / 256, 256, 0, stream>>>(deg_in, deg_out, gids,
                                                       norm_src, norm_dst, gcount, feat4);
    k_scan1<<<SCAN_NB, SCAN_B, 0, stream>>>(deg_in, off, bsum);
    k_scan2<<<1, SCAN_B, 0, stream>>>(bsum, off);
    k_scan3<<<SCAN_NB, SCAN_B, 0, stream>>>(off, bsum);
    k_scatter2<<<NB_H, 256, 0, stream>>>(src, dst, off, part_in, csr);

    // layer 1: 8-dim features -> 128 (output premultiplied by norm_src)
    k_agg1<<<(N_NODES + 255) / 256, 256, 0, stream>>>(off, csr, feat4, norm_dst, aggbuf);
    k_gemm1<<<N_NODES / 2, 256, 0, stream>>>(aggbuf, W1, b1, norm_src, hbuf);

    // layers 2..5: gather -> aggbuf, pipelined W-in-LDS / A-from-L1 GEMM -> h
    const float* Ws[4] = { W2, W3, W4, W5 };
    const float* bs[4] = { b2, b3, b4, b5 };
    dim3 ggrid((N_NODES + TM - 1) / TM, 2);
    for (int L = 0; L < 4; ++L) {
        if (aligned)
            k_agg4<<<(N_NODES * 64 + 255) / 256, 256, 0, stream>>>(off, csr,
                                                                   norm_dst, hbuf, aggbuf);
        else
            k_agg2<<<(N_NODES * 64 + 255) / 256, 256, 0, stream>>>(off, csr,
                                                                   norm_dst, hbuf, aggbuf);
        float* gout = (L < 3) ? hbuf : hco;
        k_gemm3<<<ggrid, 256, 0, stream>>>(aggbuf, Ws[L], bs[L],
                                           norm_src, (L < 3) ? 1 : 0, gout);
    }

    // pooling + head
    k_pool<<<N_NODES / POOL_CHUNK, 128, 0, stream>>>(hco, gids, gsum);
    k_head<<<N_GRAPHS, 64, 0, stream>>>(gsum, gcount, lw1, lb1, lw2, lb2, out);
}

// Round 16
// 473.469 us; speedup vs baseline: 1.0330x; 1.0330x over previous
//
#include <hip/hip_runtime.h>
#include <math.h>

#define N_NODES 50000
#define N_EDGES 800000
#define N_GRAPHS 50
#define HD 128
#define TM 64
#define POOL_CHUNK 125
#define SCAN_B 256
#define SCAN_NB ((N_NODES + SCAN_B - 1) / SCAN_B)   // 196
#define NB_H 128
#define CH_H (N_EDGES / NB_H)                        // 6250
#define NBIN2 (N_NODES / 2)                          // 25000 packed dwords

// ---------------- degree histograms: LDS uint16-packed partials, 2D grid ------------
// blockIdx.y = 0: dst -> part_in ; 1: src -> part_out (independent, parallel)
__global__ __launch_bounds__(256) void k_hist(const int* __restrict__ src,
                                              const int* __restrict__ dst,
                                              unsigned* __restrict__ part_in,
                                              unsigned* __restrict__ part_out) {
    __shared__ unsigned cnt[NBIN2];      // 100 KB
    int t = threadIdx.x, b = blockIdx.x;
    const int* idx = blockIdx.y ? src : dst;
    unsigned* outp = blockIdx.y ? part_out : part_in;
    int e0 = b * CH_H;
    for (int j = t; j < NBIN2; j += 256) cnt[j] = 0;
    __syncthreads();
    for (int e = e0 + t; e < e0 + CH_H; e += 256) {
        int i = idx[e];
        atomicAdd(&cnt[i >> 1], 1u << ((i & 1) * 16));
    }
    __syncthreads();
    for (int j = t; j < NBIN2; j += 256) outp[b * NBIN2 + j] = cnt[j];
}

// reduce partials to degrees; convert part_in to per-block exclusive prefixes
__global__ void k_dreduce(unsigned* __restrict__ part_in,
                          const unsigned* __restrict__ part_out,
                          int* __restrict__ deg_in, int* __restrict__ deg_out) {
    int j = blockIdx.x * blockDim.x + threadIdx.x;
    if (j >= NBIN2) return;
    unsigned run_i = 0, run_o = 0;
    for (int b = 0; b < NB_H; ++b) {
        unsigned pi = part_in[b * NBIN2 + j];
        unsigned po = part_out[b * NBIN2 + j];
        part_in[b * NBIN2 + j] = run_i;
        run_i += pi;
        run_o += po;
    }
    ((int2*)deg_in)[j] = make_int2((int)(run_i & 0xFFFFu), (int)(run_i >> 16));
    ((int2*)deg_out)[j] = make_int2((int)(run_o & 0xFFFFu), (int)(run_o >> 16));
}

// ---------------- norms + graph counts + layer-1 edge payload ----------------
__global__ void k_norms(const int* __restrict__ deg_in, const int* __restrict__ deg_out,
                        const int* __restrict__ gids,
                        float* norm_src, float* norm_dst, int* gcount,
                        float4* __restrict__ feat4) {
    __shared__ int hist[N_GRAPHS];
    int t = threadIdx.x;
    if (t < N_GRAPHS) hist[t] = 0;
    __syncthreads();
    int i = blockIdx.x * blockDim.x + t;
    if (i < N_NODES) {
        float di = (float)deg_in[i];
        float dq = (float)deg_out[i];
        float nd = 1.0f / sqrtf(fmaxf(di, 1.0f));
        float ns = 1.0f / sqrtf(fmaxf(dq, 1.0f));
        norm_dst[i] = nd;
        norm_src[i] = ns;
        float4 f;
        f.x = di * ns;
        f.y = (di > 3.0f) ? ns : 0.0f;
        f.z = (3.0f / di) * ns;
        f.w = (di > 4.0f) ? ns : 0.0f;
        feat4[i] = f;
        atomicAdd(&hist[gids[i]], 1);
    }
    __syncthreads();
    if (t < N_GRAPHS && hist[t] != 0) atomicAdd(&gcount[t], hist[t]);
}

// ---------------- device-wide exclusive scan, 3 phases ----------------
__global__ void k_scan1(const int* __restrict__ deg_in, int* off, int* bsum) {
    __shared__ int sh[SCAN_B];
    int t = threadIdx.x;
    int i = blockIdx.x * SCAN_B + t;
    int v = (i < N_NODES) ? deg_in[i] : 0;
    sh[t] = v;
    __syncthreads();
    for (int o = 1; o < SCAN_B; o <<= 1) {
        int u = (t >= o) ? sh[t - o] : 0;
        __syncthreads();
        sh[t] += u;
        __syncthreads();
    }
    if (i < N_NODES) off[i] = sh[t] - v;
    if (t == SCAN_B - 1) bsum[blockIdx.x] = sh[t];
}

__global__ void k_scan2(int* bsum, int* off) {
    __shared__ int sh[SCAN_B];
    int t = threadIdx.x;
    int v = (t < SCAN_NB) ? bsum[t] : 0;
    sh[t] = v;
    __syncthreads();
    for (int o = 1; o < SCAN_B; o <<= 1) {
        int u = (t >= o) ? sh[t - o] : 0;
        __syncthreads();
        sh[t] += u;
        __syncthreads();
    }
    if (t < SCAN_NB) bsum[t] = sh[t] - v;
    if (t == SCAN_B - 1) off[N_NODES] = sh[t];
}

__global__ void k_scan3(int* off, const int* __restrict__ bsum) {
    int b = blockIdx.x, t = threadIdx.x;
    int i = b * SCAN_B + t;
    if (i < N_NODES) off[i] += bsum[b];
}

// ---------------- CSR scatter, atomic-free (LDS packed rank cursors) ----------------
__global__ __launch_bounds__(256) void k_scatter2(const int* __restrict__ src,
                                                  const int* __restrict__ dst,
                                                  const int* __restrict__ off,
                                                  const unsigned* __restrict__ part_in,
                                                  int* __restrict__ csr) {
    __shared__ unsigned cur[NBIN2];
    int t = threadIdx.x, b = blockIdx.x;
    const unsigned* base = part_in + (size_t)b * NBIN2;
    for (int j = t; j < NBIN2; j += 256) cur[j] = base[j];
    __syncthreads();
    int e0 = b * CH_H;
    for (int e = e0 + t; e < e0 + CH_H; e += 256) {
        int d = dst[e];
        int sh = (d & 1) * 16;
        unsigned old = atomicAdd(&cur[d >> 1], 1u << sh);
        int rank = (int)((old >> sh) & 0xFFFFu);
        csr[off[d] + rank] = src[e];
    }
}

// ---------------- layer-1 aggregation: one float4 gather per edge ----------------
__global__ void k_agg1(const int* __restrict__ off, const int* __restrict__ csr,
                       const float4* __restrict__ feat4,
                       const float* __restrict__ ndst, float* __restrict__ agg8) {
    int i = blockIdx.x * blockDim.x + threadIdx.x;
    if (i >= N_NODES) return;
    int e0 = off[i], e1 = off[i + 1];
    float a0 = 0.f, a1 = 0.f, a2 = 0.f, a3 = 0.f;
    int e = e0;
    for (; e + 1 < e1; e += 2) {
        float4 f0 = feat4[csr[e]];
        float4 f1 = feat4[csr[e + 1]];
        a0 += f0.x + f1.x; a1 += f0.y + f1.y;
        a2 += f0.z + f1.z; a3 += f0.w + f1.w;
    }
    if (e < e1) {
        float4 f0 = feat4[csr[e]];
        a0 += f0.x; a1 += f0.y; a2 += f0.z; a3 += f0.w;
    }
    float nd = ndst[i];
    a0 *= nd; a1 *= nd; a2 *= nd; a3 *= nd;
    float4* p = (float4*)(agg8 + (size_t)i * 8);
    float4 hi = { a0, a1, a2, a3 };
    float4 lo = { -a0, -a1, -a2, -a3 };
    p[0] = hi;
    p[1] = lo;
}

// ---------------- layer-1 GEMM 8 -> 128, fused bias+relu+nsrc premult ---------------
__global__ void k_gemm1(const float* __restrict__ agg8, const float* __restrict__ W,
                        const float* __restrict__ b, const float* __restrict__ nsrc,
                        float* __restrict__ out) {
    __shared__ float Wsh[8 * 128];
    int t = threadIdx.x;
    for (int i = t; i < 1024; i += 256) Wsh[i] = W[i];
    __syncthreads();
    int row = blockIdx.x * 2 + (t >> 7);
    int j = t & 127;
    if (row >= N_NODES) return;
    const float* a = agg8 + (size_t)row * 8;
    float acc = b[j];
#pragma unroll
    for (int k = 0; k < 8; ++k) acc += a[k] * Wsh[k * 128 + j];
    out[(size_t)row * HD + j] = fmaxf(acc, 0.0f) * nsrc[row];
}

// ---------------- 128-dim aggregation, float4 half-wave-per-edge, 4-deep MLP --------
__global__ __launch_bounds__(256) void k_agg4(const int* __restrict__ off,
                                              const int* __restrict__ csr,
                                              const float* __restrict__ ndst,
                                              const float* __restrict__ h,
                                              float* __restrict__ out) {
    int wid = (blockIdx.x * blockDim.x + threadIdx.x) >> 6;
    int lane = threadIdx.x & 63;
    if (wid >= N_NODES) return;
    int half = lane >> 5;
    int q = lane & 31;
    int e0 = off[wid], e1 = off[wid + 1];
    float4 a = { 0.f, 0.f, 0.f, 0.f };
    int e = e0 + half;
    for (; e + 6 < e1; e += 8) {       // 4 edges per half, 8 per wave-iter
        int s0 = csr[e], s1 = csr[e + 2], s2 = csr[e + 4], s3 = csr[e + 6];
        float4 v0 = *(const float4*)(h + (size_t)s0 * HD + q * 4);
        float4 v1 = *(const float4*)(h + (size_t)s1 * HD + q * 4);
        float4 v2 = *(const float4*)(h + (size_t)s2 * HD + q * 4);
        float4 v3 = *(const float4*)(h + (size_t)s3 * HD + q * 4);
        a.x += v0.x + v1.x + v2.x + v3.x;
        a.y += v0.y + v1.y + v2.y + v3.y;
        a.z += v0.z + v1.z + v2.z + v3.z;
        a.w += v0.w + v1.w + v2.w + v3.w;
    }
    for (; e < e1; e += 2) {
        int s0 = csr[e];
        float4 v0 = *(const float4*)(h + (size_t)s0 * HD + q * 4);
        a.x += v0.x; a.y += v0.y; a.z += v0.z; a.w += v0.w;
    }
    a.x += __shfl_xor(a.x, 32);
    a.y += __shfl_xor(a.y, 32);
    a.z += __shfl_xor(a.z, 32);
    a.w += __shfl_xor(a.w, 32);
    if (half == 0) {
        float nd = ndst[wid];
        a.x *= nd; a.y *= nd; a.z *= nd; a.w *= nd;
        *(float4*)(out + (size_t)wid * HD + q * 4) = a;
    }
}

// ---------------- fallback float2 aggregation (h only 8B-aligned) ----------------
__global__ void k_agg2(const int* __restrict__ off, const int* __restrict__ csr,
                       const float* __restrict__ ndst,
                       const float* __restrict__ h, float* __restrict__ out) {
    int wid = (blockIdx.x * blockDim.x + threadIdx.x) >> 6;
    int lane = threadIdx.x & 63;
    if (wid >= N_NODES) return;
    int e0 = off[wid], e1 = off[wid + 1];
    float a0 = 0.f, a1 = 0.f;
    int e = e0;
    for (; e + 3 < e1; e += 4) {
        int s0 = csr[e], s1 = csr[e + 1], s2 = csr[e + 2], s3 = csr[e + 3];
        float2 v0 = *(const float2*)(h + (size_t)s0 * HD + lane * 2);
        float2 v1 = *(const float2*)(h + (size_t)s1 * HD + lane * 2);
        float2 v2 = *(const float2*)(h + (size_t)s2 * HD + lane * 2);
        float2 v3 = *(const float2*)(h + (size_t)s3 * HD + lane * 2);
        a0 += v0.x + v1.x + v2.x + v3.x;
        a1 += v0.y + v1.y + v2.y + v3.y;
    }
    for (; e < e1; ++e) {
        int s0 = csr[e];
        float2 v0 = *(const float2*)(h + (size_t)s0 * HD + lane * 2);
        a0 += v0.x; a1 += v0.y;
    }
    float nd = ndst[wid];
    float2 o; o.x = a0 * nd; o.y = a1 * nd;
    *(float2*)(out + (size_t)wid * HD + lane * 2) = o;
}

// ---------------- 64x64-tile GEMM: W in LDS (32 KB), A direct from global/L1 --------
// 16-lane jq-groups read identical A addresses (merged into one L1 request);
// A-tile (32 KB) fits L1. Only 32 KB LDS -> 4-5 blocks/CU, 16-20 waves/CU.
__global__ __launch_bounds__(256) void k_gemm3(const float* __restrict__ A,
                                               const float* __restrict__ W,
                                               const float* __restrict__ b,
                                               const float* __restrict__ nsrc,
                                               int premult,
                                               float* __restrict__ out) {
    __shared__ float Wsh[128 * 64];      // [k][j] half of W, 32 KB
    int t = threadIdx.x;
    int row0 = blockIdx.x * TM;
    int jh = blockIdx.y * 64;
    const float4* W4 = (const float4*)W;
#pragma unroll
    for (int i = 0; i < 8; ++i) {
        int idx = t + i * 256;           // 0..2047 over 128k x 16q
        int k = idx >> 4;
        int q = idx & 15;
        ((float4*)Wsh)[k * 16 + q] = W4[k * 32 + (jh >> 2) + q];
    }
    __syncthreads();
    int jq = (t & 15) * 4;               // col group within half
    int r0 = (t >> 4) * 4;               // row group
    const float* A0 = A + (size_t)min(row0 + r0 + 0, N_NODES - 1) * HD;
    const float* A1 = A + (size_t)min(row0 + r0 + 1, N_NODES - 1) * HD;
    const float* A2 = A + (size_t)min(row0 + r0 + 2, N_NODES - 1) * HD;
    const float* A3 = A + (size_t)min(row0 + r0 + 3, N_NODES - 1) * HD;
    float4 bv = *(const float4*)(b + jh + jq);
    float acc[4][4];
#pragma unroll
    for (int r = 0; r < 4; ++r) {
        acc[r][0] = bv.x; acc[r][1] = bv.y; acc[r][2] = bv.z; acc[r][3] = bv.w;
    }
#define KSTEP(wv, e0_, e1_, e2_, e3_)                                                   \
    acc[0][0] += e0_ * wv.x; acc[0][1] += e0_ * wv.y; acc[0][2] += e0_ * wv.z; acc[0][3] += e0_ * wv.w; \
    acc[1][0] += e1_ * wv.x; acc[1][1] += e1_ * wv.y; acc[1][2] += e1_ * wv.z; acc[1][3] += e1_ * wv.w; \
    acc[2][0] += e2_ * wv.x; acc[2][1] += e2_ * wv.y; acc[2][2] += e2_ * wv.z; acc[2][3] += e2_ * wv.w; \
    acc[3][0] += e3_ * wv.x; acc[3][1] += e3_ * wv.y; acc[3][2] += e3_ * wv.z; acc[3][3] += e3_ * wv.w;
#pragma unroll 2
    for (int k = 0; k < 128; k += 4) {
        float4 a0 = *(const float4*)(A0 + k);
        float4 a1 = *(const float4*)(A1 + k);
        float4 a2 = *(const float4*)(A2 + k);
        float4 a3 = *(const float4*)(A3 + k);
        float4 w0 = *(const float4*)&Wsh[(k + 0) * 64 + jq];
        float4 w1 = *(const float4*)&Wsh[(k + 1) * 64 + jq];
        float4 w2 = *(const float4*)&Wsh[(k + 2) * 64 + jq];
        float4 w3 = *(const float4*)&Wsh[(k + 3) * 64 + jq];
        KSTEP(w0, a0.x, a1.x, a2.x, a3.x)
        KSTEP(w1, a0.y, a1.y, a2.y, a3.y)
        KSTEP(w2, a0.z, a1.z, a2.z, a3.z)
        KSTEP(w3, a0.w, a1.w, a2.w, a3.w)
    }
#undef KSTEP
#pragma unroll
    for (int r = 0; r < 4; ++r) {
        int row = row0 + r0 + r;
        if (row < N_NODES) {
            float sc = premult ? nsrc[row] : 1.0f;
            float* op = out + (size_t)row * HD + jh + jq;
            float2 o01 = { fmaxf(acc[r][0], 0.f) * sc, fmaxf(acc[r][1], 0.f) * sc };
            float2 o23 = { fmaxf(acc[r][2], 0.f) * sc, fmaxf(acc[r][3], 0.f) * sc };
            *(float2*)op = o01;          // dest may be only 8B-aligned (d_out region)
            *(float2*)(op + 2) = o23;
        }
    }
}

// ---------------- mean-pool partials (125-node chunks, uniform graph id) ------------
__global__ void k_pool(const float* __restrict__ hco, const int* __restrict__ gids,
                       float* gsum) {
    int f = threadIdx.x;                 // 128
    int n0 = blockIdx.x * POOL_CHUNK;
    int g = gids[n0];
    float s = 0.f;
    for (int i = 0; i < POOL_CHUNK; ++i)
        s += hco[(size_t)(n0 + i) * HD + f];
    atomicAdd(&gsum[g * HD + f], s);
}

// ---------------- head: graph_emb, MLP, sigmoid ----------------
__global__ void k_head(const float* __restrict__ gsum, const int* __restrict__ gcount,
                       const float* __restrict__ lw1, const float* __restrict__ lb1,
                       const float* __restrict__ lw2, const float* __restrict__ lb2,
                       float* __restrict__ dout) {
    __shared__ float ge[128];
    int g = blockIdx.x, j = threadIdx.x;  // 64 threads
    float cnt = (float)gcount[g];
    float g0 = gsum[g * HD + j] / cnt;
    float g1 = gsum[g * HD + 64 + j] / cnt;
    ge[j] = g0; ge[64 + j] = g1;
    dout[N_GRAPHS + g * HD + j] = g0;
    dout[N_GRAPHS + g * HD + 64 + j] = g1;
    __syncthreads();
    float acc = lb1[j];
#pragma unroll 4
    for (int k = 0; k < 128; ++k) acc += ge[k] * lw1[k * 64 + j];
    float he = fmaxf(acc, 0.f);
    float p = he * lw2[j];
#pragma unroll
    for (int o = 32; o > 0; o >>= 1) p += __shfl_down(p, o);
    if (j == 0) dout[g] = 1.0f / (1.0f + expf(-(p + lb2[0])));
}

extern "C" void kernel_launch(void* const* d_in, const int* in_sizes, int n_in,
                              void* d_out, int out_size, void* d_ws, size_t ws_size,
                              hipStream_t stream) {
    const int* src  = (const int*)d_in[0];
    const int* dst  = (const int*)d_in[1];
    const int* gids = (const int*)d_in[2];
    const float* W1 = (const float*)d_in[3];  const float* b1 = (const float*)d_in[4];
    const float* W2 = (const float*)d_in[5];  const float* b2 = (const float*)d_in[6];
    const float* W3 = (const float*)d_in[7];  const float* b3 = (const float*)d_in[8];
    const float* W4 = (const float*)d_in[9];  const float* b4 = (const float*)d_in[10];
    const float* W5 = (const float*)d_in[11]; const float* b5 = (const float*)d_in[12];
    const float* lw1 = (const float*)d_in[13]; const float* lb1 = (const float*)d_in[14];
    const float* lw2 = (const float*)d_in[15]; const float* lb2 = (const float*)d_in[16];
    float* out = (float*)d_out;

    char* ws = (char*)d_ws;
    int*    gcount   = (int*)(ws + 0);              // 256 B
    float*  gsum     = (float*)(ws + 256);          // 25600 B
    const size_t ZERO_BYTES = 25856;
    int*    deg_in   = (int*)(ws + 26112);          // 200192 B
    int*    deg_out  = (int*)(ws + 226304);         // 200192 B
    int*    off      = (int*)(ws + 426496);         // 200192 B
    int*    csr      = (int*)(ws + 826880);         // 3200000 B
    float*  norm_src = (float*)(ws + 4026880);      // 200192 B
    float*  norm_dst = (float*)(ws + 4227072);      // 200192 B
    int*    bsum     = (int*)(ws + 4427264);        // 1024 B
    float4* feat4    = (float4*)(ws + 4428288);     // 800256 B
    float*  aggbuf   = (float*)(ws + 5228544);      // 25.6 MB (hist partials + agg)
    float*  hws      = (float*)(ws + 30828544);     // 25.6 MB (16B-aligned h rows)
    const size_t WS_NEEDED = 30828544 + 25600000;

    unsigned* part_in  = (unsigned*)aggbuf;
    unsigned* part_out = (unsigned*)aggbuf + NB_H * NBIN2;

    float* hco = out + (N_GRAPHS + N_GRAPHS * HD);  // layer-5 output = h_co region
    bool aligned = (ws_size >= WS_NEEDED);
    float* hbuf = aligned ? hws : hco;

    hipMemsetAsync(ws, 0, ZERO_BYTES, stream);

    k_hist<<<dim3(NB_H, 2), 256, 0, stream>>>(src, dst, part_in, part_out);
    k_dreduce<<<(NBIN2 + 255) / 256, 256, 0, stream>>>(part_in, part_out,
                                                       deg_in, deg_out);
    k_norms<<<(N_NODES + 255) / 256, 256, 0, stream>>>(deg_in, deg_out, gids,
                                                       norm_src, norm_dst, gcount, feat4);
    k_scan1<<<SCAN_NB, SCAN_B, 0, stream>>>(deg_in, off, bsum);
    k_scan2<<<1, SCAN_B, 0, stream>>>(bsum, off);
    k_scan3<<<SCAN_NB, SCAN_B, 0, stream>>>(off, bsum);
    k_scatter2<<<NB_H, 256, 0, stream>>>(src, dst, off, part_in, csr);

    // layer 1: 8-dim features -> 128 (output premultiplied by norm_src)
    k_agg1<<<(N_NODES + 255) / 256, 256, 0, stream>>>(off, csr, feat4, norm_dst, aggbuf);
    k_gemm1<<<N_NODES / 2, 256, 0, stream>>>(aggbuf, W1, b1, norm_src, hbuf);

    // layers 2..5: gather -> aggbuf, W-in-LDS / A-from-L1 GEMM -> h (premult for 2-4)
    const float* Ws[4] = { W2, W3, W4, W5 };
    const float* bs[4] = { b2, b3, b4, b5 };
    dim3 ggrid((N_NODES + TM - 1) / TM, 2);
    for (int L = 0; L < 4; ++L) {
        if (aligned)
            k_agg4<<<(N_NODES * 64 + 255) / 256, 256, 0, stream>>>(off, csr,
                                                                   norm_dst, hbuf, aggbuf);
        else
            k_agg2<<<(N_NODES * 64 + 255) / 256, 256, 0, stream>>>(off, csr,
                                                                   norm_dst, hbuf, aggbuf);
        float* gout = (L < 3) ? hbuf : hco;
        k_gemm3<<<ggrid, 256, 0, stream>>>(aggbuf, Ws[L], bs[L],
                                           norm_src, (L < 3) ? 1 : 0, gout);
    }

    // pooling + head
    k_pool<<<N_NODES / POOL_CHUNK, 128, 0, stream>>>(hco, gids, gsum);
    k_head<<<N_GRAPHS, 64, 0, stream>>>(gsum, gcount, lw1, lb1, lw2, lb2, out);
}